// Round 9
// baseline (99.689 us; speedup 1.0000x reference)
//
#include <hip/hip_runtime.h>
#include <math.h>

#define NHEADS 16
#define HS     128
#define NOPT   512
#define TB     128      // tokens per block (4 waves x 32)
#define OC     32       // options per chunk
#define NCH    16       // chunks
#define EMB    2048
#define LOG2E  1.44269504088896340736f
#define THRD   11.0f    // defer-max threshold (log2 units)

typedef short bf16x8 __attribute__((ext_vector_type(8)));
typedef _Float16 f16x8 __attribute__((ext_vector_type(8)));
typedef unsigned short u16x8 __attribute__((ext_vector_type(8)));
typedef float f32x4 __attribute__((ext_vector_type(4)));
typedef float f32x16 __attribute__((ext_vector_type(16)));
typedef unsigned u32x4 __attribute__((ext_vector_type(4)));

__device__ __forceinline__ unsigned short f2bf(float f) {
    union { float f; unsigned u; } v; v.f = f;
    unsigned r = v.u + 0x7FFFu + ((v.u >> 16) & 1u);
    return (unsigned short)(r >> 16);
}
__device__ __forceinline__ float bf2f(unsigned short h) {
    union { unsigned u; float f; } v; v.u = ((unsigned)h) << 16;
    return v.f;
}
__device__ __forceinline__ unsigned short f2h(float f) {   // RNE f32->f16 bits
    const _Float16 h = (_Float16)f;
    return __builtin_bit_cast(unsigned short, h);
}
__device__ __forceinline__ void gll16(const void* gptr, void* lptr) {
    __builtin_amdgcn_global_load_lds(
        (const __attribute__((address_space(1))) void*)gptr,
        (__attribute__((address_space(3))) void*)lptr,
        16, 0, 0);
}
__device__ __forceinline__ unsigned pkrtz(float lo, float hi) {
    unsigned r;
    asm("v_cvt_pkrtz_f16_f32 %0, %1, %2" : "=v"(r) : "v"(lo), "v"(hi));
    return r;
}
__device__ __forceinline__ void pl32swap(unsigned &a, unsigned &b) {
    asm volatile("v_permlane32_swap_b32 %0, %1" : "+v"(a), "+v"(b));
}
__device__ __forceinline__ f32x16 mfma32h(f16x8 a, f16x8 b, f32x16 c) {
    return __builtin_amdgcn_mfma_f32_32x32x16_f16(a, b, c, 0, 0, 0);
}

// ---------------- workspace image layout (ushorts, f16 bits) ----------------
// W': [h][c] chunk = 32 opt x 128 k f16, PRE-SCALED by invT*log2e,
//     row-swizzled col^((opt&15)<<3).                 (8 KB/chunk)
// C : [h][c] chunk = C^T 128 a x 32 opt f16, swizzled opt^(((a>>1)&3)<<3). (8 KB)
#define WCH    4096
#define CCH    4096
#define WS_C0  (NHEADS * NCH * WCH)                               // 2 MB worth
#define WS_TOTAL_BYTES ((size_t)(WS_C0 + NHEADS * NCH * CCH) * 2) // 4 MB

// ============ prep: f32 -> pre-swizzled f16 chunk images ============
__global__ __launch_bounds__(256) void vq_prep(const float* __restrict__ W,
                                               const float* __restrict__ C,
                                               const float* __restrict__ temp,
                                               unsigned short* __restrict__ ws)
{
    const int b = blockIdx.x, t = threadIdx.x;
    if (b < NHEADS * NCH) {                 // W chunk (scaled, single f16)
        const float scW = (1.0f / temp[0]) * LOG2E;
        const float* src = W + (size_t)b * OC * HS;
        unsigned short* dst = ws + (size_t)b * WCH;
        for (int k = 0; k < 16; ++k) {
            const int e = k * 256 + t;      // 4096 elems
            const int opt = e >> 7, col = e & 127;
            dst[opt * 128 + (col ^ ((opt & 15) << 3))] = f2h(src[e] * scW);
        }
    } else {                                // C chunk -> C^T[a][opt] f16
        const int b2 = b - NHEADS * NCH;
        const float* src = C + (size_t)b2 * OC * HS;
        unsigned short* dst = ws + WS_C0 + (size_t)b2 * CCH;
        for (int k = 0; k < 16; ++k) {
            const int e = k * 256 + t;
            const int opt = e >> 7, a = e & 127;
            dst[a * 32 + (opt ^ (((a >> 1) & 3) << 3))] = f2h(src[e]);
        }
    }
}

// ============ main: f16 swapped-QK 32x32 MFMA, online softmax, in-reg P ====
// R9: fit the <=128-total-reg occupancy bin (m69: waves/SIMD step at 64/128/256).
// O(64 AGPR) + xf(32) leave 32 VGPRs: single QK chain (was 2), pv in-place over
// S, max3-shaped reduce. LDS 32 KB dbuf -> 4 blocks/CU; grid 1024 = exactly 4/CU.
__global__ __launch_bounds__(256, 4) void vq_main(
    const float* __restrict__ x, const unsigned short* __restrict__ ws,
    float* __restrict__ out)
{
    __shared__ unsigned short wbuf[2][WCH];   // 16 KB (dbuf W chunk)
    __shared__ unsigned short cbuf[2][CCH];   // 16 KB (dbuf C^T chunk)

    const int t = threadIdx.x, l = t & 63, w = t >> 6;
    const int la = l & 31, hf = l >> 5;
    const int b = blockIdx.x;
    const int head = ((b & 7) << 1) | ((b >> 3) & 1);   // 2 heads per XCD
    const int n0 = (b >> 4) * TB;

    const unsigned short* gwbase = ws + (size_t)(head * NCH) * WCH;
    const unsigned short* gcbase = ws + WS_C0 + (size_t)(head * NCH) * CCH;

    // ---- prologue DMA: chunk 0 -> slot 0 ----
    {
        const char* gw = (const char*)gwbase + w * 1024 + l * 16;
        gll16(gw, (char*)&wbuf[0][0] + w * 1024);
        const char* gc = (const char*)gcbase + w * 1024 + l * 16;
        gll16(gc, (char*)&cbuf[0][0] + w * 1024);
        // each wave stages 1KB of each image... wait: 8KB image / 4 waves = 2KB
        gll16(gw + 4096, (char*)&wbuf[0][0] + 4096 + w * 1024);
        gll16(gc + 4096, (char*)&cbuf[0][0] + 4096 + w * 1024);
    }

    // ---- x row as f16 B-fragments (32 VGPR) ----
    f16x8 xf[8];
    {
        const float* xr = x + (size_t)(n0 + w * 32 + la) * EMB + head * HS + hf * 8;
        #pragma unroll
        for (int kb = 0; kb < 8; ++kb) {
            const float4 v0 = *(const float4*)(xr + kb * 16);
            const float4 v1 = *(const float4*)(xr + kb * 16 + 4);
            const float vv[8] = {v0.x, v0.y, v0.z, v0.w, v1.x, v1.y, v1.z, v1.w};
            u16x8 hh;
            #pragma unroll
            for (int j = 0; j < 8; ++j) hh[j] = f2h(vv[j]);
            xf[kb] = __builtin_bit_cast(f16x8, hh);
        }
    }

    f32x16 O0 = (f32x16)0.0f, O1 = (f32x16)0.0f, O2 = (f32x16)0.0f, O3 = (f32x16)0.0f;
    float M = -1.0e30f, sacc = 0.0f;

    asm volatile("s_waitcnt vmcnt(0)" ::: "memory");   // chunk 0 landed
    __builtin_amdgcn_s_barrier();

    for (int c = 0; c < NCH; ++c) {
        const int cur = c & 1;
        // ---- prefetch chunk c+1 into the other slot (last read: iter c-1) ----
        if (c + 1 < NCH) {
            const char* gw = (const char*)(gwbase + (size_t)(c + 1) * WCH) + w * 1024 + l * 16;
            char* lw = (char*)&wbuf[cur ^ 1][0] + w * 1024;
            gll16(gw, lw); gll16(gw + 4096, lw + 4096);
            const char* gc = (const char*)(gcbase + (size_t)(c + 1) * CCH) + w * 1024 + l * 16;
            char* lc = (char*)&cbuf[cur ^ 1][0] + w * 1024;
            gll16(gc, lc); gll16(gc + 4096, lc + 4096);
        }

        // ---- QK^T swapped: S^T[opt][tok] = W' · x^T (single chain, 8 MFMAs) ----
        f32x16 S = (f32x16)0.0f;
        const unsigned short* wb = &wbuf[cur][0];
        #pragma unroll
        for (int kb = 0; kb < 8; ++kb) {
            const int idx = la * 128 + ((kb * 16 + hf * 8) ^ ((la & 15) << 3));
            S = mfma32h(*(const f16x8*)&wb[idx], xf[kb], S);
        }

        // ---- online softmax (per token = per lane); max3-shaped reduce ----
        float cmax = fmaxf(S[0], S[1]);
        #pragma unroll
        for (int i = 2; i < 16; i += 2) cmax = fmaxf(fmaxf(cmax, S[i]), S[i + 1]);
        cmax = fmaxf(cmax, __shfl_xor(cmax, 32));
        if (__any(cmax > M + THRD)) {          // rare rescale (defer-max, T13)
            const float Mn = fmaxf(M, cmax);
            const float fr = exp2f(M - Mn);    // first chunk: exp2(-1e30)=0
            M = Mn;
            sacc *= fr;
            #pragma unroll
            for (int q = 0; q < 16; ++q) {
                const int row = (q & 3) + 8 * (q >> 2) + 4 * hf;
                const float f = __shfl(fr, row);
                O0[q] *= f; O1[q] *= f; O2[q] *= f; O3[q] *= f;
            }
        }
        #pragma unroll
        for (int q = 0; q < 16; ++q) S[q] = exp2f(S[q] - M);   // pv in-place
        {   // tree sum
            float s8[8];
            #pragma unroll
            for (int i = 0; i < 8; ++i) s8[i] = S[2 * i] + S[2 * i + 1];
            sacc += ((s8[0] + s8[1]) + (s8[2] + s8[3])) +
                    ((s8[4] + s8[5]) + (s8[6] + s8[7]));
        }

        // ---- P -> f16 A-fragments fully in-register (T12, verified layout) ----
        unsigned pk0 = pkrtz(S[0],  S[1]),  pk1 = pkrtz(S[2],  S[3]);
        unsigned pk2 = pkrtz(S[4],  S[5]),  pk3 = pkrtz(S[6],  S[7]);
        unsigned pk4 = pkrtz(S[8],  S[9]),  pk5 = pkrtz(S[10], S[11]);
        unsigned pk6 = pkrtz(S[12], S[13]), pk7 = pkrtz(S[14], S[15]);
        pl32swap(pk0, pk2);
        pl32swap(pk1, pk3);
        pl32swap(pk4, pk6);
        pl32swap(pk5, pk7);
        const f16x8 pa0 = __builtin_bit_cast(f16x8, (u32x4){pk0, pk1, pk2, pk3});
        const f16x8 pa1 = __builtin_bit_cast(f16x8, (u32x4){pk4, pk5, pk6, pk7});

        // ---- PV: O += P · C (A=P regs, B=C^T LDS) ----
        const unsigned short* cb = &cbuf[cur][0];
        {
            const int a0 = la;
            const int sw0 = ((a0 >> 1) & 3) << 3;
            O0 = mfma32h(pa0, *(const f16x8*)&cb[a0 * 32 + ((hf * 8) ^ sw0)], O0);
            O0 = mfma32h(pa1, *(const f16x8*)&cb[a0 * 32 + ((16 + hf * 8) ^ sw0)], O0);
            const int a1 = 32 + la;
            const int sw1 = ((a1 >> 1) & 3) << 3;
            O1 = mfma32h(pa0, *(const f16x8*)&cb[a1 * 32 + ((hf * 8) ^ sw1)], O1);
            O1 = mfma32h(pa1, *(const f16x8*)&cb[a1 * 32 + ((16 + hf * 8) ^ sw1)], O1);
            const int a2 = 64 + la;
            const int sw2 = ((a2 >> 1) & 3) << 3;
            O2 = mfma32h(pa0, *(const f16x8*)&cb[a2 * 32 + ((hf * 8) ^ sw2)], O2);
            O2 = mfma32h(pa1, *(const f16x8*)&cb[a2 * 32 + ((16 + hf * 8) ^ sw2)], O2);
            const int a3 = 96 + la;
            const int sw3 = ((a3 >> 1) & 3) << 3;
            O3 = mfma32h(pa0, *(const f16x8*)&cb[a3 * 32 + ((hf * 8) ^ sw3)], O3);
            O3 = mfma32h(pa1, *(const f16x8*)&cb[a3 * 32 + ((16 + hf * 8) ^ sw3)], O3);
        }

        // ---- c+1's DMA landed (issued a full chunk-compute ago, L2-resident) ----
        asm volatile("s_waitcnt vmcnt(0)" ::: "memory");
        if (c + 1 < NCH) __builtin_amdgcn_s_barrier();
    }

    // ---- epilogue: normalize by 1/sum, coalesced stores ----
    const float stot = sacc + __shfl_xor(sacc, 32);
    const float rs = 1.0f / stot;
    #pragma unroll
    for (int q = 0; q < 16; ++q) {
        const int row = (q & 3) + 8 * (q >> 2) + 4 * hf;
        const float rq = __shfl(rs, row);
        float* op = out + (size_t)(n0 + w * 32 + row) * EMB + head * HS + la;
        op[0]  = O0[q] * rq;
        op[32] = O1[q] * rq;
        op[64] = O2[q] * rq;
        op[96] = O3[q] * rq;
    }
}

// ============ fallback (Round-2 kernel, no workspace needed) ============
__global__ __launch_bounds__(256, 2) void vq_fwd_mfma(
    const float* __restrict__ x, const float* __restrict__ W,
    const float* __restrict__ C, const float* __restrict__ temp,
    float* __restrict__ out)
{
    __shared__ unsigned short xh_lds[64 * HS];
    __shared__ unsigned short xl_lds[64 * HS];
    __shared__ unsigned short wst[2][64 * HS];
    __shared__ unsigned short p_lds[4][16 * 64];

    const int t = threadIdx.x, l = t & 63, w = t >> 6, lr = l & 15, lk = l >> 4;
    const int b = blockIdx.x;
    const int h = ((b & 7) << 1) | ((b >> 3) & 1);
    const int n0 = (b >> 4) * 64;
    const float invT = 1.0f / temp[0];

    #pragma unroll
    for (int kk = 0; kk < 4; ++kk) {
        const int g = t + 256 * kk;
        const int row = g >> 4, c8 = (g & 15) * 8;
        const float* src = x + (size_t)(n0 + row) * EMB + h * HS + c8;
        const float4 v0 = *(const float4*)src;
        const float4 v1 = *(const float4*)(src + 4);
        float vv[8] = {v0.x, v0.y, v0.z, v0.w, v1.x, v1.y, v1.z, v1.w};
        u16x8 hh, ll;
        #pragma unroll
        for (int j = 0; j < 8; ++j) {
            const unsigned short hb = f2bf(vv[j]);
            hh[j] = hb; ll[j] = f2bf(vv[j] - bf2f(hb));
        }
        const int idx = row * HS + (c8 ^ ((row & 7) << 3));
        *(u16x8*)&xh_lds[idx] = hh;
        *(u16x8*)&xl_lds[idx] = ll;
    }

    f32x4 acc[32];
    #pragma unroll
    for (int i = 0; i < 32; ++i) acc[i] = f32x4{0.f, 0.f, 0.f, 0.f};
    bf16x8 axh[4], axl[4];

    #pragma unroll
    for (int c = 0; c < 8; ++c) {
        if (c) __syncthreads();
        #pragma unroll
        for (int kk = 0; kk < 4; ++kk) {
            const int g = t + 256 * kk;
            const int row = g >> 4, c8 = (g & 15) * 8;
            const float* src = W + ((size_t)h * NOPT + c * 64 + row) * HS + c8;
            const float4 v0 = *(const float4*)src;
            const float4 v1 = *(const float4*)(src + 4);
            float vv[8] = {v0.x, v0.y, v0.z, v0.w, v1.x, v1.y, v1.z, v1.w};
            u16x8 hh, ll;
            #pragma unroll
            for (int j = 0; j < 8; ++j) {
                const unsigned short hb = f2bf(vv[j]);
                hh[j] = hb; ll[j] = f2bf(vv[j] - bf2f(hb));
            }
            const int idx = row * HS + (c8 ^ ((row & 7) << 3));
            *(u16x8*)&wst[0][idx] = hh;
            *(u16x8*)&wst[1][idx] = ll;
        }
        __syncthreads();
        if (c == 0) {
            const int arow = w * 16 + lr;
            #pragma unroll
            for (int ks = 0; ks < 4; ++ks) {
                const int ai = arow * HS + ((lk * 8 + ks * 32) ^ ((arow & 7) << 3));
                axh[ks] = *(const bf16x8*)&xh_lds[ai];
                axl[ks] = *(const bf16x8*)&xl_lds[ai];
            }
        }
        #pragma unroll
        for (int nt = 0; nt < 4; ++nt) {
            const int brow = nt * 16 + lr;
            #pragma unroll
            for (int ks = 0; ks < 4; ++ks) {
                const int bi = brow * HS + ((lk * 8 + ks * 32) ^ ((brow & 7) << 3));
                const bf16x8 bh = *(const bf16x8*)&wst[0][bi];
                const bf16x8 bl = *(const bf16x8*)&wst[1][bi];
                acc[c*4+nt] = __builtin_amdgcn_mfma_f32_16x16x32_bf16(axh[ks], bh, acc[c*4+nt], 0, 0, 0);
                acc[c*4+nt] = __builtin_amdgcn_mfma_f32_16x16x32_bf16(axl[ks], bh, acc[c*4+nt], 0, 0, 0);
                acc[c*4+nt] = __builtin_amdgcn_mfma_f32_16x16x32_bf16(axh[ks], bl, acc[c*4+nt], 0, 0, 0);
            }
        }
    }

    float mx[4], rsn[4];
    #pragma unroll
    for (int r = 0; r < 4; ++r) {
        float m = -3.0e38f;
        #pragma unroll
        for (int i = 0; i < 32; ++i) m = fmaxf(m, acc[i][r]);
        m *= invT;
        #pragma unroll
        for (int s = 1; s < 16; s <<= 1) m = fmaxf(m, __shfl_xor(m, s));
        float sum = 0.f;
        #pragma unroll
        for (int i = 0; i < 32; ++i) sum += exp2f((acc[i][r] * invT - m) * LOG2E);
        #pragma unroll
        for (int s = 1; s < 16; s <<= 1) sum += __shfl_xor(sum, s);
        mx[r] = m; rsn[r] = 1.0f / sum;
    }

    f32x4 oacc[8];
    #pragma unroll
    for (int i = 0; i < 8; ++i) oacc[i] = f32x4{0.f, 0.f, 0.f, 0.f};
    const int pr_ = t & 31, ag = t >> 5;
    #pragma unroll
    for (int c = 0; c < 8; ++c) {
        __syncthreads();
        {
            const float* c0p = C + ((size_t)h * NOPT + c * 64 + 2 * pr_) * HS + ag * 16;
            float va[16], vb[16];
            #pragma unroll
            for (int q = 0; q < 4; ++q) {
                const float4 u0 = ((const float4*)c0p)[q];
                const float4 u1 = ((const float4*)(c0p + HS))[q];
                va[q*4+0] = u0.x; va[q*4+1] = u0.y; va[q*4+2] = u0.z; va[q*4+3] = u0.w;
                vb[q*4+0] = u1.x; vb[q*4+1] = u1.y; vb[q*4+2] = u1.z; vb[q*4+3] = u1.w;
            }
            unsigned* ct32 = (unsigned*)&wst[0][0];
            #pragma unroll
            for (int j = 0; j < 16; ++j) {
                const int a = ag * 16 + j;
                const unsigned pkv = (unsigned)f2bf(va[j]) | ((unsigned)f2bf(vb[j]) << 16);
                ct32[a * 32 + (pr_ ^ ((a & 7) << 2))] = pkv;
            }
        }
        #pragma unroll
        for (int nt = 0; nt < 4; ++nt) {
            #pragma unroll
            for (int r = 0; r < 4; ++r) {
                const float p = exp2f((acc[c*4+nt][r] * invT - mx[r]) * LOG2E);
                const int prow = lk * 4 + r;
                const int pcol = nt * 16 + lr;
                p_lds[w][prow * 64 + (pcol ^ ((prow & 7) << 3))] = f2bf(p);
            }
        }
        __syncthreads();
        #pragma unroll
        for (int ks = 0; ks < 2; ++ks) {
            const int ai = lr * 64 + ((lk * 8 + ks * 32) ^ ((lr & 7) << 3));
            const bf16x8 pa = *(const bf16x8*)&p_lds[w][ai];
            #pragma unroll
            for (int nt = 0; nt < 8; ++nt) {
                const int brow = nt * 16 + lr;
                const int bi = brow * 64 + ((lk * 8 + ks * 32) ^ ((brow & 7) << 3));
                const bf16x8 cbv = *(const bf16x8*)&wst[0][bi];
                oacc[nt] = __builtin_amdgcn_mfma_f32_16x16x32_bf16(pa, cbv, oacc[nt], 0, 0, 0);
            }
        }
    }

    #pragma unroll
    for (int nt = 0; nt < 8; ++nt) {
        #pragma unroll
        for (int r = 0; r < 4; ++r) {
            const int tok = n0 + w * 16 + lk * 4 + r;
            out[(size_t)tok * EMB + h * HS + nt * 16 + lr] = oacc[nt][r] * rsn[r];
        }
    }
}

extern "C" void kernel_launch(void* const* d_in, const int* in_sizes, int n_in,
                              void* d_out, int out_size, void* d_ws, size_t ws_size,
                              hipStream_t stream) {
    const float* x = (const float*)d_in[0];
    const float* W = (const float*)d_in[1];
    const float* C = (const float*)d_in[2];
    const float* T = (const float*)d_in[3];
    float* out     = (float*)d_out;

    const int ntok = in_sizes[0] / EMB;   // 8192

    if (ws_size >= WS_TOTAL_BYTES) {
        hipLaunchKernelGGL(vq_prep, dim3(NHEADS * NCH * 2), dim3(256), 0, stream,
                           W, C, T, (unsigned short*)d_ws);
        const int nblk = (ntok / TB) * NHEADS;   // 1024
        hipLaunchKernelGGL(vq_main, dim3(nblk), dim3(256), 0, stream,
                           x, (const unsigned short*)d_ws, out);
    } else {
        const int nblk = (ntok / 64) * NHEADS;   // 2048
        hipLaunchKernelGGL(vq_fwd_mfma, dim3(nblk), dim3(256), 0, stream,
                           x, W, C, T, out);
    }
}

// Round 10
// 73.758 us; speedup vs baseline: 1.3516x; 1.3516x over previous
//
#include <hip/hip_runtime.h>
#include <math.h>

#define NHEADS 16
#define HS     128
#define NOPT   512
#define TB     128      // tokens per block (4 waves x 32)
#define OC     32       // options per image sub-chunk (image layout unchanged)
#define NCH    16       // image sub-chunks per head
#define NITER  8        // main loop processes 2 sub-chunks per iteration
#define EMB    2048
#define LOG2E  1.44269504088896340736f
#define THRD   11.0f    // defer-max threshold (log2 units)

typedef short bf16x8 __attribute__((ext_vector_type(8)));
typedef _Float16 f16x8 __attribute__((ext_vector_type(8)));
typedef unsigned short u16x8 __attribute__((ext_vector_type(8)));
typedef float f32x4 __attribute__((ext_vector_type(4)));
typedef float f32x16 __attribute__((ext_vector_type(16)));
typedef unsigned u32x4 __attribute__((ext_vector_type(4)));

__device__ __forceinline__ unsigned short f2bf(float f) {
    union { float f; unsigned u; } v; v.f = f;
    unsigned r = v.u + 0x7FFFu + ((v.u >> 16) & 1u);
    return (unsigned short)(r >> 16);
}
__device__ __forceinline__ float bf2f(unsigned short h) {
    union { unsigned u; float f; } v; v.u = ((unsigned)h) << 16;
    return v.f;
}
__device__ __forceinline__ unsigned short f2h(float f) {   // RNE f32->f16 bits
    const _Float16 h = (_Float16)f;
    return __builtin_bit_cast(unsigned short, h);
}
__device__ __forceinline__ void gll16(const void* gptr, void* lptr) {
    __builtin_amdgcn_global_load_lds(
        (const __attribute__((address_space(1))) void*)gptr,
        (__attribute__((address_space(3))) void*)lptr,
        16, 0, 0);
}
__device__ __forceinline__ unsigned pkrtz(float lo, float hi) {
    unsigned r;
    asm("v_cvt_pkrtz_f16_f32 %0, %1, %2" : "=v"(r) : "v"(lo), "v"(hi));
    return r;
}
__device__ __forceinline__ void pl32swap(unsigned &a, unsigned &b) {
    asm volatile("v_permlane32_swap_b32 %0, %1" : "+v"(a), "+v"(b));
}
__device__ __forceinline__ f32x16 mfma32h(f16x8 a, f16x8 b, f32x16 c) {
    return __builtin_amdgcn_mfma_f32_32x32x16_f16(a, b, c, 0, 0, 0);
}

// ---------------- workspace image layout (ushorts, f16 bits) ----------------
// W': [h][c] sub-chunk = 32 opt x 128 k f16, PRE-SCALED by invT*log2e,
//     row-swizzled col^((opt&15)<<3).                 (8 KB each)
// C : [h][c] sub-chunk = C^T 128 a x 32 opt f16, swizzled opt^(((a>>1)&3)<<3).
#define WCH    4096
#define CCH    4096
#define WS_C0  (NHEADS * NCH * WCH)
#define WS_TOTAL_BYTES ((size_t)(WS_C0 + NHEADS * NCH * CCH) * 2) // 4 MB

// ============ prep: f32 -> pre-swizzled f16 chunk images (same as R8) ========
__global__ __launch_bounds__(256) void vq_prep(const float* __restrict__ W,
                                               const float* __restrict__ C,
                                               const float* __restrict__ temp,
                                               unsigned short* __restrict__ ws)
{
    const int b = blockIdx.x, t = threadIdx.x;
    if (b < NHEADS * NCH) {                 // W chunk (scaled, single f16)
        const float scW = (1.0f / temp[0]) * LOG2E;
        const float* src = W + (size_t)b * OC * HS;
        unsigned short* dst = ws + (size_t)b * WCH;
        for (int k = 0; k < 16; ++k) {
            const int e = k * 256 + t;
            const int opt = e >> 7, col = e & 127;
            dst[opt * 128 + (col ^ ((opt & 15) << 3))] = f2h(src[e] * scW);
        }
    } else {                                // C chunk -> C^T[a][opt] f16
        const int b2 = b - NHEADS * NCH;
        const float* src = C + (size_t)b2 * OC * HS;
        unsigned short* dst = ws + WS_C0 + (size_t)b2 * CCH;
        for (int k = 0; k < 16; ++k) {
            const int e = k * 256 + t;
            const int opt = e >> 7, a = e & 127;
            dst[a * 32 + (opt ^ (((a >> 1) & 3) << 3))] = f2h(src[e]);
        }
    }
}

// ============ main: 64 options per iteration (2 sub-chunks), f16 MFMA =======
// R9 lesson (twice): forcing sub-148-reg occupancy spills; run at 2 waves/SIMD
// and attack per-chunk fixed overhead instead: one barrier pair, one rescale
// check, one staging wait per 64 options. 4 indep QK chains, 16-MFMA PV block.
__global__ __launch_bounds__(256, 2) void vq_main(
    const float* __restrict__ x, const unsigned short* __restrict__ ws,
    float* __restrict__ out)
{
    __shared__ unsigned short wbuf[2][2 * WCH];   // 32 KB (dbuf, W sub-pair)
    __shared__ unsigned short cbuf[2][2 * CCH];   // 32 KB (dbuf, C sub-pair)

    const int t = threadIdx.x, l = t & 63, w = t >> 6;
    const int la = l & 31, hf = l >> 5;
    const int b = blockIdx.x;
    const int head = ((b & 7) << 1) | ((b >> 3) & 1);   // 2 heads per XCD
    const int n0 = (b >> 4) * TB;

    const char* gwbase = (const char*)(ws + (size_t)(head * NCH) * WCH);
    const char* gcbase = (const char*)(ws + WS_C0 + (size_t)(head * NCH) * CCH);

    // ---- prologue DMA: iteration 0's 16KB W-pair + 16KB C-pair ----
    {
        const char* gw = gwbase + w * 4096 + l * 16;
        char* lw = (char*)&wbuf[0][0] + w * 4096;
        const char* gc = gcbase + w * 4096 + l * 16;
        char* lc = (char*)&cbuf[0][0] + w * 4096;
        #pragma unroll
        for (int i = 0; i < 4; ++i) { gll16(gw + i * 1024, lw + i * 1024);
                                      gll16(gc + i * 1024, lc + i * 1024); }
    }

    // ---- x row as f16 B-fragments (32 VGPR) ----
    f16x8 xf[8];
    {
        const float* xr = x + (size_t)(n0 + w * 32 + la) * EMB + head * HS + hf * 8;
        #pragma unroll
        for (int kb = 0; kb < 8; ++kb) {
            const float4 v0 = *(const float4*)(xr + kb * 16);
            const float4 v1 = *(const float4*)(xr + kb * 16 + 4);
            const float vv[8] = {v0.x, v0.y, v0.z, v0.w, v1.x, v1.y, v1.z, v1.w};
            u16x8 hh;
            #pragma unroll
            for (int j = 0; j < 8; ++j) hh[j] = f2h(vv[j]);
            xf[kb] = __builtin_bit_cast(f16x8, hh);
        }
    }

    f32x16 O0 = (f32x16)0.0f, O1 = (f32x16)0.0f, O2 = (f32x16)0.0f, O3 = (f32x16)0.0f;
    float M = -1.0e30f, sacc = 0.0f;

    asm volatile("s_waitcnt vmcnt(0)" ::: "memory");   // iter-0 data landed
    __builtin_amdgcn_s_barrier();

    for (int cc = 0; cc < NITER; ++cc) {
        const int cur = cc & 1;
        // ---- prefetch iteration cc+1 (buffer last read in iter cc-1) ----
        if (cc + 1 < NITER) {
            const char* gw = gwbase + (size_t)(cc + 1) * 16384 + w * 4096 + l * 16;
            char* lw = (char*)&wbuf[cur ^ 1][0] + w * 4096;
            const char* gc = gcbase + (size_t)(cc + 1) * 16384 + w * 4096 + l * 16;
            char* lc = (char*)&cbuf[cur ^ 1][0] + w * 4096;
            #pragma unroll
            for (int i = 0; i < 4; ++i) { gll16(gw + i * 1024, lw + i * 1024);
                                          gll16(gc + i * 1024, lc + i * 1024); }
        }

        // ---- QK^T: S0 (opts 0-31), S1 (opts 32-63); 2 chains each ----
        f32x16 s0a = (f32x16)0.0f, s0b = (f32x16)0.0f;
        f32x16 s1a = (f32x16)0.0f, s1b = (f32x16)0.0f;
        const unsigned short* wb0 = &wbuf[cur][0];
        const unsigned short* wb1 = &wbuf[cur][WCH];
        #pragma unroll
        for (int kb = 0; kb < 8; ++kb) {
            const int idx = la * 128 + ((kb * 16 + hf * 8) ^ ((la & 15) << 3));
            const f16x8 w0 = *(const f16x8*)&wb0[idx];
            const f16x8 w1 = *(const f16x8*)&wb1[idx];
            if (kb & 1) { s0b = mfma32h(w0, xf[kb], s0b); s1b = mfma32h(w1, xf[kb], s1b); }
            else        { s0a = mfma32h(w0, xf[kb], s0a); s1a = mfma32h(w1, xf[kb], s1a); }
        }
        f32x16 S0 = s0a + s0b;
        f32x16 S1 = s1a + s1b;

        // ---- online softmax over 64 options (one check per iteration) ----
        float cmax = fmaxf(S0[0], S1[0]);
        #pragma unroll
        for (int i = 1; i < 16; ++i) cmax = fmaxf(fmaxf(cmax, S0[i]), S1[i]);
        cmax = fmaxf(cmax, __shfl_xor(cmax, 32));
        if (__any(cmax > M + THRD)) {          // rare rescale (defer-max, T13)
            const float Mn = fmaxf(M, cmax);
            const float fr = exp2f(M - Mn);    // first iteration: exp2(-1e30)=0
            M = Mn;
            sacc *= fr;
            #pragma unroll
            for (int q = 0; q < 16; ++q) {
                const int row = (q & 3) + 8 * (q >> 2) + 4 * hf;
                const float f = __shfl(fr, row);
                O0[q] *= f; O1[q] *= f; O2[q] *= f; O3[q] *= f;
            }
        }
        #pragma unroll
        for (int q = 0; q < 16; ++q) { S0[q] = exp2f(S0[q] - M); S1[q] = exp2f(S1[q] - M); }
        {   // tree sum over both halves
            float s8[8];
            #pragma unroll
            for (int i = 0; i < 8; ++i)
                s8[i] = (S0[2 * i] + S0[2 * i + 1]) + (S1[2 * i] + S1[2 * i + 1]);
            sacc += ((s8[0] + s8[1]) + (s8[2] + s8[3])) +
                    ((s8[4] + s8[5]) + (s8[6] + s8[7]));
        }

        // ---- P -> f16 A-fragments in-register (verified T12 recipe, x2) ----
        unsigned pk0 = pkrtz(S0[0],  S0[1]),  pk1 = pkrtz(S0[2],  S0[3]);
        unsigned pk2 = pkrtz(S0[4],  S0[5]),  pk3 = pkrtz(S0[6],  S0[7]);
        unsigned pk4 = pkrtz(S0[8],  S0[9]),  pk5 = pkrtz(S0[10], S0[11]);
        unsigned pk6 = pkrtz(S0[12], S0[13]), pk7 = pkrtz(S0[14], S0[15]);
        pl32swap(pk0, pk2); pl32swap(pk1, pk3);
        pl32swap(pk4, pk6); pl32swap(pk5, pk7);
        const f16x8 pa0 = __builtin_bit_cast(f16x8, (u32x4){pk0, pk1, pk2, pk3});
        const f16x8 pa1 = __builtin_bit_cast(f16x8, (u32x4){pk4, pk5, pk6, pk7});
        unsigned qk0 = pkrtz(S1[0],  S1[1]),  qk1 = pkrtz(S1[2],  S1[3]);
        unsigned qk2 = pkrtz(S1[4],  S1[5]),  qk3 = pkrtz(S1[6],  S1[7]);
        unsigned qk4 = pkrtz(S1[8],  S1[9]),  qk5 = pkrtz(S1[10], S1[11]);
        unsigned qk6 = pkrtz(S1[12], S1[13]), qk7 = pkrtz(S1[14], S1[15]);
        pl32swap(qk0, qk2); pl32swap(qk1, qk3);
        pl32swap(qk4, qk6); pl32swap(qk5, qk7);
        const f16x8 pa2 = __builtin_bit_cast(f16x8, (u32x4){qk0, qk1, qk2, qk3});
        const f16x8 pa3 = __builtin_bit_cast(f16x8, (u32x4){qk4, qk5, qk6, qk7});

        // ---- PV: O += P · C over 64 options (4 indep chains x 4 MFMAs) ----
        const unsigned short* cb0 = &cbuf[cur][0];
        const unsigned short* cb1 = &cbuf[cur][CCH];
        #pragma unroll
        for (int nt = 0; nt < 4; ++nt) {
            const int a = nt * 32 + la;
            const int sw = ((a >> 1) & 3) << 3;
            const int i0 = a * 32 + ((hf * 8) ^ sw);
            const int i1 = a * 32 + ((16 + hf * 8) ^ sw);
            f32x16& O = (nt == 0) ? O0 : (nt == 1) ? O1 : (nt == 2) ? O2 : O3;
            O = mfma32h(pa0, *(const f16x8*)&cb0[i0], O);
            O = mfma32h(pa1, *(const f16x8*)&cb0[i1], O);
            O = mfma32h(pa2, *(const f16x8*)&cb1[i0], O);
            O = mfma32h(pa3, *(const f16x8*)&cb1[i1], O);
        }

        // ---- cc+1's DMA had a full 64-option compute to land ----
        asm volatile("s_waitcnt vmcnt(0)" ::: "memory");
        if (cc + 1 < NITER) __builtin_amdgcn_s_barrier();
    }

    // ---- epilogue: normalize by 1/sum, coalesced stores ----
    const float stot = sacc + __shfl_xor(sacc, 32);
    const float rs = 1.0f / stot;
    #pragma unroll
    for (int q = 0; q < 16; ++q) {
        const int row = (q & 3) + 8 * (q >> 2) + 4 * hf;
        const float rq = __shfl(rs, row);
        float* op = out + (size_t)(n0 + w * 32 + row) * EMB + head * HS + la;
        op[0]  = O0[q] * rq;
        op[32] = O1[q] * rq;
        op[64] = O2[q] * rq;
        op[96] = O3[q] * rq;
    }
}

// ============ fallback (Round-2 kernel, no workspace needed) ============
__global__ __launch_bounds__(256, 2) void vq_fwd_mfma(
    const float* __restrict__ x, const float* __restrict__ W,
    const float* __restrict__ C, const float* __restrict__ temp,
    float* __restrict__ out)
{
    __shared__ unsigned short xh_lds[64 * HS];
    __shared__ unsigned short xl_lds[64 * HS];
    __shared__ unsigned short wst[2][64 * HS];
    __shared__ unsigned short p_lds[4][16 * 64];

    const int t = threadIdx.x, l = t & 63, w = t >> 6, lr = l & 15, lk = l >> 4;
    const int b = blockIdx.x;
    const int h = ((b & 7) << 1) | ((b >> 3) & 1);
    const int n0 = (b >> 4) * 64;
    const float invT = 1.0f / temp[0];

    #pragma unroll
    for (int kk = 0; kk < 4; ++kk) {
        const int g = t + 256 * kk;
        const int row = g >> 4, c8 = (g & 15) * 8;
        const float* src = x + (size_t)(n0 + row) * EMB + h * HS + c8;
        const float4 v0 = *(const float4*)src;
        const float4 v1 = *(const float4*)(src + 4);
        float vv[8] = {v0.x, v0.y, v0.z, v0.w, v1.x, v1.y, v1.z, v1.w};
        u16x8 hh, ll;
        #pragma unroll
        for (int j = 0; j < 8; ++j) {
            const unsigned short hb = f2bf(vv[j]);
            hh[j] = hb; ll[j] = f2bf(vv[j] - bf2f(hb));
        }
        const int idx = row * HS + (c8 ^ ((row & 7) << 3));
        *(u16x8*)&xh_lds[idx] = hh;
        *(u16x8*)&xl_lds[idx] = ll;
    }

    f32x4 acc[32];
    #pragma unroll
    for (int i = 0; i < 32; ++i) acc[i] = f32x4{0.f, 0.f, 0.f, 0.f};
    bf16x8 axh[4], axl[4];

    #pragma unroll
    for (int c = 0; c < 8; ++c) {
        if (c) __syncthreads();
        #pragma unroll
        for (int kk = 0; kk < 4; ++kk) {
            const int g = t + 256 * kk;
            const int row = g >> 4, c8 = (g & 15) * 8;
            const float* src = W + ((size_t)h * NOPT + c * 64 + row) * HS + c8;
            const float4 v0 = *(const float4*)src;
            const float4 v1 = *(const float4*)(src + 4);
            float vv[8] = {v0.x, v0.y, v0.z, v0.w, v1.x, v1.y, v1.z, v1.w};
            u16x8 hh, ll;
            #pragma unroll
            for (int j = 0; j < 8; ++j) {
                const unsigned short hb = f2bf(vv[j]);
                hh[j] = hb; ll[j] = f2bf(vv[j] - bf2f(hb));
            }
            const int idx = row * HS + (c8 ^ ((row & 7) << 3));
            *(u16x8*)&wst[0][idx] = hh;
            *(u16x8*)&wst[1][idx] = ll;
        }
        __syncthreads();
        if (c == 0) {
            const int arow = w * 16 + lr;
            #pragma unroll
            for (int ks = 0; ks < 4; ++ks) {
                const int ai = arow * HS + ((lk * 8 + ks * 32) ^ ((arow & 7) << 3));
                axh[ks] = *(const bf16x8*)&xh_lds[ai];
                axl[ks] = *(const bf16x8*)&xl_lds[ai];
            }
        }
        #pragma unroll
        for (int nt = 0; nt < 4; ++nt) {
            const int brow = nt * 16 + lr;
            #pragma unroll
            for (int ks = 0; ks < 4; ++ks) {
                const int bi = brow * HS + ((lk * 8 + ks * 32) ^ ((brow & 7) << 3));
                const bf16x8 bh = *(const bf16x8*)&wst[0][bi];
                const bf16x8 bl = *(const bf16x8*)&wst[1][bi];
                acc[c*4+nt] = __builtin_amdgcn_mfma_f32_16x16x32_bf16(axh[ks], bh, acc[c*4+nt], 0, 0, 0);
                acc[c*4+nt] = __builtin_amdgcn_mfma_f32_16x16x32_bf16(axl[ks], bh, acc[c*4+nt], 0, 0, 0);
                acc[c*4+nt] = __builtin_amdgcn_mfma_f32_16x16x32_bf16(axh[ks], bl, acc[c*4+nt], 0, 0, 0);
            }
        }
    }

    float mx[4], rsn[4];
    #pragma unroll
    for (int r = 0; r < 4; ++r) {
        float m = -3.0e38f;
        #pragma unroll
        for (int i = 0; i < 32; ++i) m = fmaxf(m, acc[i][r]);
        m *= invT;
        #pragma unroll
        for (int s = 1; s < 16; s <<= 1) m = fmaxf(m, __shfl_xor(m, s));
        float sum = 0.f;
        #pragma unroll
        for (int i = 0; i < 32; ++i) sum += exp2f((acc[i][r] * invT - m) * LOG2E);
        #pragma unroll
        for (int s = 1; s < 16; s <<= 1) sum += __shfl_xor(sum, s);
        mx[r] = m; rsn[r] = 1.0f / sum;
    }

    f32x4 oacc[8];
    #pragma unroll
    for (int i = 0; i < 8; ++i) oacc[i] = f32x4{0.f, 0.f, 0.f, 0.f};
    const int pr_ = t & 31, ag = t >> 5;
    #pragma unroll
    for (int c = 0; c < 8; ++c) {
        __syncthreads();
        {
            const float* c0p = C + ((size_t)h * NOPT + c * 64 + 2 * pr_) * HS + ag * 16;
            float va[16], vb[16];
            #pragma unroll
            for (int q = 0; q < 4; ++q) {
                const float4 u0 = ((const float4*)c0p)[q];
                const float4 u1 = ((const float4*)(c0p + HS))[q];
                va[q*4+0] = u0.x; va[q*4+1] = u0.y; va[q*4+2] = u0.z; va[q*4+3] = u0.w;
                vb[q*4+0] = u1.x; vb[q*4+1] = u1.y; vb[q*4+2] = u1.z; vb[q*4+3] = u1.w;
            }
            unsigned* ct32 = (unsigned*)&wst[0][0];
            #pragma unroll
            for (int j = 0; j < 16; ++j) {
                const int a = ag * 16 + j;
                const unsigned pkv = (unsigned)f2bf(va[j]) | ((unsigned)f2bf(vb[j]) << 16);
                ct32[a * 32 + (pr_ ^ ((a & 7) << 2))] = pkv;
            }
        }
        #pragma unroll
        for (int nt = 0; nt < 4; ++nt) {
            #pragma unroll
            for (int r = 0; r < 4; ++r) {
                const float p = exp2f((acc[c*4+nt][r] * invT - mx[r]) * LOG2E);
                const int prow = lk * 4 + r;
                const int pcol = nt * 16 + lr;
                p_lds[w][prow * 64 + (pcol ^ ((prow & 7) << 3))] = f2bf(p);
            }
        }
        __syncthreads();
        #pragma unroll
        for (int ks = 0; ks < 2; ++ks) {
            const int ai = lr * 64 + ((lk * 8 + ks * 32) ^ ((lr & 7) << 3));
            const bf16x8 pa = *(const bf16x8*)&p_lds[w][ai];
            #pragma unroll
            for (int nt = 0; nt < 8; ++nt) {
                const int brow = nt * 16 + lr;
                const int bi = brow * 64 + ((lk * 8 + ks * 32) ^ ((brow & 7) << 3));
                const bf16x8 cbv = *(const bf16x8*)&wst[0][bi];
                oacc[nt] = __builtin_amdgcn_mfma_f32_16x16x32_bf16(pa, cbv, oacc[nt], 0, 0, 0);
            }
        }
    }

    #pragma unroll
    for (int nt = 0; nt < 8; ++nt) {
        #pragma unroll
        for (int r = 0; r < 4; ++r) {
            const int tok = n0 + w * 16 + lk * 4 + r;
            out[(size_t)tok * EMB + h * HS + nt * 16 + lr] = oacc[nt][r] * rsn[r];
        }
    }
}

extern "C" void kernel_launch(void* const* d_in, const int* in_sizes, int n_in,
                              void* d_out, int out_size, void* d_ws, size_t ws_size,
                              hipStream_t stream) {
    const float* x = (const float*)d_in[0];
    const float* W = (const float*)d_in[1];
    const float* C = (const float*)d_in[2];
    const float* T = (const float*)d_in[3];
    float* out     = (float*)d_out;

    const int ntok = in_sizes[0] / EMB;   // 8192

    if (ws_size >= WS_TOTAL_BYTES) {
        hipLaunchKernelGGL(vq_prep, dim3(NHEADS * NCH * 2), dim3(256), 0, stream,
                           W, C, T, (unsigned short*)d_ws);
        const int nblk = (ntok / TB) * NHEADS;   // 1024
        hipLaunchKernelGGL(vq_main, dim3(nblk), dim3(256), 0, stream,
                           x, (const unsigned short*)d_ws, out);
    } else {
        const int nblk = (ntok / 64) * NHEADS;   // 2048
        hipLaunchKernelGGL(vq_fwd_mfma, dim3(nblk), dim3(256), 0, stream,
                           x, W, C, T, out);
    }
}